// Round 17
// baseline (125.544 us; speedup 1.0000x reference)
//
#include <hip/hip_runtime.h>
#include <hip/hip_bf16.h>

#define H_DIM 768
#define S_LEN 128
#define NT 12  // 768 / 64 K-tiles

typedef __attribute__((ext_vector_type(8))) short short8;
typedef __attribute__((ext_vector_type(4))) float f32x4;

__device__ __forceinline__ void gload_lds16(const void* g, void* l) {
  __builtin_amdgcn_global_load_lds(
      (const __attribute__((address_space(1))) unsigned int*)g,
      (__attribute__((address_space(3))) unsigned int*)l, 16, 0, 0);
}

// ---------------- Kernel 0: prep — prefix scans + pad zeroing ----------------
// Blocks 0..63: x1 sequence sq -> dest1, cnts1, zero pad rows [n1, n1p).
// Blocks 64..95: x2 pair pp, b0 and b1 compacted SEPARATELY within one panel:
// b0 rows [0,n2_0) pad to n2p0; b1 rows [n2p0, n2p0+n2_1) pad to n2p0+n2p1.
// Every 16-row fragment of the panel belongs wholly to one b.
__global__ __launch_bounds__(256) void prep_kernel(
    const int* __restrict__ mask1, const int* __restrict__ mask2,
    int* __restrict__ dest1, int* __restrict__ dest2,
    int* __restrict__ cnts1, int* __restrict__ c20, int* __restrict__ c21,
    int* __restrict__ cp0,
    unsigned short* __restrict__ xc1, unsigned short* __restrict__ xc2p) {
  const int blk = blockIdx.x;
  const int tid = threadIdx.x;
  const int lane = tid & 63, wv = tid >> 6;
  __shared__ int wsum[4];
  if (blk < 64) {  // x1 sequence
    const int sq = blk;
    if (tid < 128) {
      const int m = mask1[sq * S_LEN + tid] ? 1 : 0;
      const unsigned long long bal = __ballot(m);
      const int pre = __popcll(bal & ((1ull << lane) - 1ull));
      if (lane == 0) wsum[wv] = __popcll(bal);
      __syncthreads();
      const int base = (wv == 1) ? wsum[0] : 0;
      dest1[sq * S_LEN + tid] = m ? (base + pre) : -1;
      if (tid == 0) cnts1[sq] = wsum[0] + wsum[1];
    } else {
      __syncthreads();
    }
    const int n = wsum[0] + wsum[1];
    const int np = (n + 15) & ~15;
    unsigned short* xc = xc1 + (size_t)sq * S_LEN * H_DIM;
    const int nz = (np - n) * 96;  // short8 chunks in pad rows
    for (int c = tid; c < nz; c += 256) {
      const int row = n + c / 96;
      *reinterpret_cast<short8*>(xc + (size_t)row * H_DIM + (c % 96) * 8) =
          (short8){0, 0, 0, 0, 0, 0, 0, 0};
    }
  } else {  // x2 pair (b0 = waves 0,1; b1 = waves 2,3)
    const int pp = blk - 64;
    const int m = mask2[pp * 256 + tid] ? 1 : 0;
    const unsigned long long bal = __ballot(m);
    const int pre = __popcll(bal & ((1ull << lane) - 1ull));
    if (lane == 0) wsum[wv] = __popcll(bal);
    __syncthreads();
    const int n0 = wsum[0] + wsum[1];
    const int n1b = wsum[2] + wsum[3];
    const int np0 = (n0 + 15) & ~15;
    const int np1 = (n1b + 15) & ~15;
    int base;
    if (wv == 0)      base = 0;
    else if (wv == 1) base = wsum[0];
    else if (wv == 2) base = np0;
    else              base = np0 + wsum[2];
    dest2[pp * 256 + tid] = m ? (base + pre) : -1;
    if (tid == 0) { c20[pp] = n0; c21[pp] = n1b; cp0[pp] = np0; }
    // zero two pad regions: [n0, np0) and [np0+n1b, np0+np1)
    const int z1 = np0 - n0, z2 = np1 - n1b;
    unsigned short* xc = xc2p + (size_t)pp * 256 * H_DIM;
    const int nz = (z1 + z2) * 96;
    for (int c = tid; c < nz; c += 256) {
      const int rz = c / 96;
      const int row = (rz < z1) ? (n0 + rz) : (np0 + n1b + (rz - z1));
      *reinterpret_cast<short8*>(xc + (size_t)row * H_DIM + (c % 96) * 8) =
          (short8){0, 0, 0, 0, 0, 0, 0, 0};
    }
  }
}

// ---------------- Kernel 1: per-token L2 normalize -> compacted bf16 rows ----------------
__global__ __launch_bounds__(256) void normc_kernel(
    const float* __restrict__ x1, const float* __restrict__ x2,
    const int* __restrict__ dest1, const int* __restrict__ dest2,
    unsigned short* __restrict__ xc1, unsigned short* __restrict__ xc2p) {
  const int gid = blockIdx.x;  // 0..16383
  const bool is1 = (gid < 8192);
  int d;
  const float* row;
  unsigned short* orow;
  if (is1) {
    const int sq = gid >> 7, tok = gid & 127;
    d = dest1[sq * S_LEN + tok];
    row = x1 + (size_t)gid * H_DIM;
    orow = xc1 + ((size_t)sq * S_LEN + d) * H_DIM;
  } else {
    const int t2 = gid - 8192;
    const int pp = t2 >> 8, tokp = t2 & 255;
    d = dest2[pp * 256 + tokp];
    row = x2 + (size_t)t2 * H_DIM;
    orow = xc2p + ((size_t)pp * 256 + d) * H_DIM;
  }
  if (d < 0) return;  // block-uniform exit for masked tokens
  const int tid = threadIdx.x;
  float4 v = make_float4(0.f, 0.f, 0.f, 0.f);
  float ss = 0.f;
  if (tid < 192) {
    v = reinterpret_cast<const float4*>(row)[tid];
    ss = v.x * v.x + v.y * v.y + v.z * v.z + v.w * v.w;
  }
#pragma unroll
  for (int o = 32; o > 0; o >>= 1) ss += __shfl_down(ss, o);
  __shared__ float ws[4];
  if ((tid & 63) == 0) ws[tid >> 6] = ss;
  __syncthreads();
  const float scale = 1.0f / sqrtf(ws[0] + ws[1] + ws[2] + ws[3]);
  if (tid < 192) {
    union { ushort4 u; __hip_bfloat16 h[4]; } o;
    o.h[0] = __float2bfloat16(v.x * scale);
    o.h[1] = __float2bfloat16(v.y * scale);
    o.h[2] = __float2bfloat16(v.z * scale);
    o.h[3] = __float2bfloat16(v.w * scale);
    reinterpret_cast<ushort4*>(orow)[tid] = o.u;
  }
}

// ---------------- Kernel 2: one block = (a, b-pair), compacted 128 x ntotp tile ----------------
// R16's concat-B structure with the spill fixed: per-b 16-aligned sub-panels
// and a TWO-PASS row-max epilogue (one live running max at a time) keep the
// register budget at R13's proven 64 VGPR + 64 AGPR = 128 -> 2 blocks/CU,
// no scratch. K-loop is the R10/R13 proven shape.
__global__ __launch_bounds__(512, 4) void rwmd_kernel(
    const unsigned short* __restrict__ xc1, const unsigned short* __restrict__ xc2p,
    const int* __restrict__ cnts1, const int* __restrict__ c20,
    const int* __restrict__ c21, const int* __restrict__ cp0,
    float* __restrict__ out) {
  __shared__ __align__(16) unsigned char smem[49152];          // 48 KB
  unsigned short* const Al = (unsigned short*)smem;            // [<=128][64], 16 KB
  unsigned short* const Bl = (unsigned short*)(smem + 16384);  // [<=256][64], 32 KB
  float* const rpart0 = (float*)smem;                          // overlay [4][128]
  float* const rpart1 = (float*)(smem + 2048);                 // overlay [4][128]
  float* const cpart = (float*)(smem + 4096);                  // overlay [2][256]

  const int a = blockIdx.x >> 5;   // 64 a's
  const int bp = blockIdx.x & 31;  // 32 b-pairs
  const int n1 = cnts1[a];
  const int n2_0 = c20[bp], n2_1 = c21[bp], np0 = cp0[bp];
  const int n1p = (n1 + 15) & ~15;
  const int ntotp = np0 + ((n2_1 + 15) & ~15);  // total padded panel rows
  const int tid = threadIdx.x;
  const int lane = tid & 63;
  const int w = tid >> 6;
  const int wm = w >> 2, wn = w & 3;
  const int g = lane >> 4, rl = lane & 15;

  const unsigned short* A0 = xc1 + (size_t)a * (S_LEN * H_DIM);
  const unsigned short* B0 = xc2p + (size_t)bp * (256 * H_DIM);

  f32x4 acc[4][4];  // row = wm*64+i*16+g*4+r, col = wn*64+j*16+rl
#pragma unroll
  for (int i = 0; i < 4; ++i)
#pragma unroll
    for (int j = 0; j < 4; ++j) acc[i][j] = (f32x4){0.f, 0.f, 0.f, 0.f};

  for (int t = 0; t < NT; ++t) {
    __syncthreads();  // previous compute done before DMA overwrites LDS
    const int k0 = t * 64;
    // A: 1024 chunks (2/thread); B: 2048 chunks (4/thread). Linear LDS dest,
    // inverse-swizzled global source chunk (rule 21). Row guards skip pad space.
#pragma unroll
    for (int q = 0; q < 2; ++q) {
      const int s = q * 512 + tid;
      const int row = s >> 3;
      const int cb = (s & 7) ^ (row & 7);
      if (row < n1p)
        gload_lds16(A0 + (size_t)row * H_DIM + k0 + cb * 8, Al + s * 8);
    }
#pragma unroll
    for (int q = 0; q < 4; ++q) {
      const int s = q * 512 + tid;
      const int row = s >> 3;  // 0..255
      const int cb = (s & 7) ^ (row & 7);
      if (row < ntotp)
        gload_lds16(B0 + (size_t)row * H_DIM + k0 + cb * 8, Bl + s * 8);
    }
    __syncthreads();  // drains vmcnt(0)
#pragma unroll
    for (int kf = 0; kf < 2; ++kf) {
      const int slot = (kf * 4 + g) ^ (rl & 7);  // frag row&7 == rl&7
      short8 av[4], bv[4];
#pragma unroll
      for (int i = 0; i < 4; ++i)
        if (wm * 64 + i * 16 < n1p)  // wave-uniform
          av[i] = *reinterpret_cast<const short8*>(
              &Al[(wm * 64 + i * 16 + rl) * 64 + slot * 8]);
#pragma unroll
      for (int j = 0; j < 4; ++j)
        if (wn * 64 + j * 16 < ntotp)  // wave-uniform
          bv[j] = *reinterpret_cast<const short8*>(
              &Bl[(wn * 64 + j * 16 + rl) * 64 + slot * 8]);
      __builtin_amdgcn_s_setprio(1);
#pragma unroll
      for (int i = 0; i < 4; ++i)
#pragma unroll
        for (int j = 0; j < 4; ++j)
          if (wm * 64 + i * 16 < n1p && wn * 64 + j * 16 < ntotp)
            acc[i][j] = __builtin_amdgcn_mfma_f32_16x16x32_bf16(
                av[i], bv[j], acc[i][j], 0, 0, 0);
      __builtin_amdgcn_s_setprio(0);
    }
  }

  __syncthreads();  // staging LDS dead -> safe to overlay rpart/cpart

  // ---- TWO-PASS row-maxes (one live running max per pass -> no spill) ----
  // pass 1: b0 (cols [0, n2_0))
#pragma unroll
  for (int i = 0; i < 4; ++i) {
#pragma unroll
    for (int r = 0; r < 4; ++r) {
      float pm = -INFINITY;
#pragma unroll
      for (int j = 0; j < 4; ++j) {
        const int col = wn * 64 + j * 16 + rl;
        pm = fmaxf(pm, (col < n2_0) ? acc[i][j][r] : -INFINITY);
      }
#pragma unroll
      for (int o = 1; o < 16; o <<= 1) pm = fmaxf(pm, __shfl_xor(pm, o));
      if (rl == 0) rpart0[wn * S_LEN + wm * 64 + i * 16 + g * 4 + r] = pm;
    }
  }
  // pass 2: b1 (cols [np0, np0 + n2_1))
#pragma unroll
  for (int i = 0; i < 4; ++i) {
#pragma unroll
    for (int r = 0; r < 4; ++r) {
      float pm = -INFINITY;
#pragma unroll
      for (int j = 0; j < 4; ++j) {
        const int col = wn * 64 + j * 16 + rl;
        pm = fmaxf(pm, (col >= np0 && col < np0 + n2_1) ? acc[i][j][r] : -INFINITY);
      }
#pragma unroll
      for (int o = 1; o < 16; o <<= 1) pm = fmaxf(pm, __shfl_xor(pm, o));
      if (rl == 0) rpart1[wn * S_LEN + wm * 64 + i * 16 + g * 4 + r] = pm;
    }
  }
  // col-maxes over real A rows
#pragma unroll
  for (int j = 0; j < 4; ++j) {
    float cm = -INFINITY;
#pragma unroll
    for (int i = 0; i < 4; ++i)
#pragma unroll
      for (int r = 0; r < 4; ++r) {
        const int row = wm * 64 + i * 16 + g * 4 + r;
        cm = fmaxf(cm, (row < n1) ? acc[i][j][r] : -INFINITY);
      }
    cm = fmaxf(cm, __shfl_xor(cm, 16));
    cm = fmaxf(cm, __shfl_xor(cm, 32));
    if (g == 0) cpart[wm * 256 + wn * 64 + j * 16 + rl] = cm;
  }
  __syncthreads();

  // ---- final means: wave 0 -> b0, wave 1 -> b1 ----
  if (w < 2) {
    const float* rp = w ? rpart1 : rpart0;
    const int clo = w ? np0 : 0;
    const int chi = w ? (np0 + n2_1) : n2_0;
    const int n2w = w ? n2_1 : n2_0;
    float v1 = 0.f, v2 = 0.f;
#pragma unroll
    for (int q = 0; q < 2; ++q) {
      const int r = lane + q * 64;
      if (r < n1)
        v1 += fmaxf(fmaxf(rp[r], rp[S_LEN + r]),
                    fmaxf(rp[2 * S_LEN + r], rp[3 * S_LEN + r]));
    }
#pragma unroll
    for (int q = 0; q < 4; ++q) {
      const int c = lane + q * 64;
      if (c >= clo && c < chi) v2 += fmaxf(cpart[c], cpart[256 + c]);
    }
#pragma unroll
    for (int o = 32; o > 0; o >>= 1) {
      v1 += __shfl_down(v1, o);
      v2 += __shfl_down(v2, o);
    }
    if (lane == 0)
      out[a * 64 + bp * 2 + w] = 0.5f * (v1 / (float)n1 + v2 / (float)n2w);
  }
}

extern "C" void kernel_launch(void* const* d_in, const int* in_sizes, int n_in,
                              void* d_out, int out_size, void* d_ws, size_t ws_size,
                              hipStream_t stream) {
  const float* x1 = (const float*)d_in[0];
  const int* mask1 = (const int*)d_in[1];
  const float* x2 = (const float*)d_in[2];
  const int* mask2 = (const int*)d_in[3];
  float* out = (float*)d_out;

  unsigned short* xc1 = (unsigned short*)d_ws;                 // 12.58 MB compacted A
  unsigned short* xc2p = xc1 + (size_t)64 * S_LEN * H_DIM;     // 12.58 MB pair panels
  int* dest1 = (int*)(xc2p + (size_t)32 * 256 * H_DIM);        // 64*128
  int* dest2 = dest1 + 64 * S_LEN;                             // 32*256
  int* cnts1 = dest2 + 32 * 256;                               // 64
  int* c20 = cnts1 + 64;                                       // 32
  int* c21 = c20 + 32;                                         // 32
  int* cp0 = c21 + 32;                                         // 32

  prep_kernel<<<96, 256, 0, stream>>>(mask1, mask2, dest1, dest2, cnts1, c20,
                                      c21, cp0, xc1, xc2p);
  normc_kernel<<<16384, 256, 0, stream>>>(x1, x2, dest1, dest2, xc1, xc2p);
  rwmd_kernel<<<64 * 32, 512, 0, stream>>>(xc1, xc2p, cnts1, c20, c21, cp0, out);
}

// Round 18
// 107.295 us; speedup vs baseline: 1.1701x; 1.1701x over previous
//
#include <hip/hip_runtime.h>
#include <hip/hip_bf16.h>

#define H_DIM 768
#define S_LEN 128
#define NT 12        // 768 / 64 K-tiles
#define GSTRIDE 512  // fixed granule stride (Npad/16 <= 512)

typedef __attribute__((ext_vector_type(8))) short short8;
typedef __attribute__((ext_vector_type(4))) float f32x4;

__device__ __forceinline__ void gload_lds16(const void* g, void* l) {
  __builtin_amdgcn_global_load_lds(
      (const __attribute__((address_space(1))) unsigned int*)g,
      (__attribute__((address_space(3))) unsigned int*)l, 16, 0, 0);
}

// ---------------- K0: per-seq ballot scan -> seq-local compact index + counts ----------------
__global__ __launch_bounds__(128) void prep_kernel(
    const int* __restrict__ mask1, const int* __restrict__ mask2,
    int* __restrict__ dest, int* __restrict__ cnts) {
  const int sq = blockIdx.x;  // 0..127 (0..63 x1, 64..127 x2)
  const int* mask = (sq < 64) ? (mask1 + sq * S_LEN) : (mask2 + (sq - 64) * S_LEN);
  const int tid = threadIdx.x;
  const int lane = tid & 63, wv = tid >> 6;
  const int m = mask[tid] ? 1 : 0;
  const unsigned long long bal = __ballot(m);
  const int pre = __popcll(bal & ((1ull << lane) - 1ull));
  __shared__ int wsum[2];
  if (lane == 0) wsum[wv] = __popcll(bal);
  __syncthreads();
  const int base = (wv == 1) ? wsum[0] : 0;
  dest[sq * S_LEN + tid] = m ? (base + pre) : -1;
  if (tid == 0) cnts[sq] = wsum[0] + wsum[1];
}

// ---------------- K1: offsets (16-aligned exclusive scan) + per-granule valid bitmasks ----------------
__global__ __launch_bounds__(512) void scan_kernel(
    const int* __restrict__ cnts, int* __restrict__ off1, int* __restrict__ off2,
    unsigned* __restrict__ vbitsM, unsigned* __restrict__ vbitsN,
    int* __restrict__ dims) {
  __shared__ int so1[65], so2[65];
  const int tid = threadIdx.x;
  if (tid == 0) {
    int o = 0;
    for (int s = 0; s < 64; ++s) { so1[s] = o; o += (cnts[s] + 15) & ~15; }
    so1[64] = o;
    o = 0;
    for (int s = 0; s < 64; ++s) { so2[s] = o; o += (cnts[64 + s] + 15) & ~15; }
    so2[64] = o;
  }
  __syncthreads();
  if (tid < 65) { off1[tid] = so1[tid]; off2[tid] = so2[tid]; }
  if (tid == 0) {
    const int Mpad = (so1[64] + 127) & ~127;
    const int Npad = (so2[64] + 127) & ~127;
    dims[0] = Mpad; dims[1] = Npad; dims[2] = Mpad >> 7; dims[3] = Npad >> 7;
  }
  // granule valid bits (granules never straddle seqs: offsets are 16-aligned)
  const int g = tid;  // 0..511
  unsigned bm = 0, bn = 0;
  const int r0 = g * 16;
  if (r0 < so1[64]) {
    int s = 0;
    while (so1[s + 1] <= r0) ++s;
    const int b0 = so1[s], nv = cnts[s];
    for (int k = 0; k < 16; ++k)
      if (r0 + k - b0 < nv) bm |= (1u << k);
  }
  if (r0 < so2[64]) {
    int s = 0;
    while (so2[s + 1] <= r0) ++s;
    const int b0 = so2[s], nv = cnts[64 + s];
    for (int k = 0; k < 16; ++k)
      if (r0 + k - b0 < nv) bn |= (1u << k);
  }
  vbitsM[g] = bm;
  vbitsN[g] = bn;
}

// ---------------- K2: per-token L2 normalize -> globally compacted bf16 rows ----------------
__global__ __launch_bounds__(256) void normc_kernel(
    const float* __restrict__ x1, const float* __restrict__ x2,
    const int* __restrict__ dest, const int* __restrict__ off1,
    const int* __restrict__ off2,
    unsigned short* __restrict__ xc1, unsigned short* __restrict__ xc2) {
  const int gid = blockIdx.x;  // 0..16383
  const int sg = gid >> 7, tok = gid & 127;
  const int d = dest[sg * S_LEN + tok];
  if (d < 0) return;  // block-uniform exit for masked tokens
  const bool is1 = (gid < 8192);
  const float* row = is1 ? (x1 + (size_t)gid * H_DIM)
                         : (x2 + (size_t)(gid - 8192) * H_DIM);
  const int grow = (is1 ? off1[sg] : off2[sg - 64]) + d;
  unsigned short* orow = (is1 ? xc1 : xc2) + (size_t)grow * H_DIM;
  const int tid = threadIdx.x;
  float4 v = make_float4(0.f, 0.f, 0.f, 0.f);
  float ss = 0.f;
  if (tid < 192) {
    v = reinterpret_cast<const float4*>(row)[tid];
    ss = v.x * v.x + v.y * v.y + v.z * v.z + v.w * v.w;
  }
#pragma unroll
  for (int o = 32; o > 0; o >>= 1) ss += __shfl_down(ss, o);
  __shared__ float ws[4];
  if ((tid & 63) == 0) ws[tid >> 6] = ss;
  __syncthreads();
  const float scale = 1.0f / sqrtf(ws[0] + ws[1] + ws[2] + ws[3]);
  if (tid < 192) {
    union { ushort4 u; __hip_bfloat16 h[4]; } o;
    o.h[0] = __float2bfloat16(v.x * scale);
    o.h[1] = __float2bfloat16(v.y * scale);
    o.h[2] = __float2bfloat16(v.z * scale);
    o.h[3] = __float2bfloat16(v.w * scale);
    reinterpret_cast<ushort4*>(orow)[tid] = o.u;
  }
}

// ---------------- K3: ONE dense GEMM over all compacted tokens ----------------
// R13's proven 128x128 / 4-wave / BK=64 skeleton, guard-free (pad data is
// zero). Epilogue: per 16x16 fragment (always within one (a,b) seq pair by
// 16-alignment), bitmask-validated row/col granule maxes stored to global
// (unique writer per entry, no atomics).
__global__ __launch_bounds__(256, 4) void gemm_kernel(
    const unsigned short* __restrict__ xc1, const unsigned short* __restrict__ xc2,
    const unsigned* __restrict__ vbitsM, const unsigned* __restrict__ vbitsN,
    const int* __restrict__ dims,
    float* __restrict__ rowgran, float* __restrict__ colgran) {
  __shared__ __align__(16) unsigned short Al[128 * 64];  // 16 KB
  __shared__ __align__(16) unsigned short Bl[128 * 64];  // 16 KB
  const int Nt = dims[3];
  const int nwork = dims[2] * Nt;
  const int bid = blockIdx.x;
  if (bid >= nwork) return;
  const int mt = bid / Nt, nt = bid - mt * Nt;
  const int tid = threadIdx.x;
  const int lane = tid & 63, w = tid >> 6;
  const int wm = w >> 1, wn = w & 1;
  const int g = lane >> 4, rl = lane & 15;
  const unsigned short* A0 = xc1 + (size_t)mt * 128 * H_DIM;
  const unsigned short* B0 = xc2 + (size_t)nt * 128 * H_DIM;

  f32x4 acc[4][4];  // row = wm*64+i*16+g*4+r, col = wn*64+j*16+rl
#pragma unroll
  for (int i = 0; i < 4; ++i)
#pragma unroll
    for (int j = 0; j < 4; ++j) acc[i][j] = (f32x4){0.f, 0.f, 0.f, 0.f};

  for (int t = 0; t < NT; ++t) {
    __syncthreads();
    const int k0 = t * 64;
    // 1024 16B-chunks per operand, 4 each per thread. Linear LDS dest,
    // inverse-swizzled global source chunk (rule 21).
#pragma unroll
    for (int q = 0; q < 4; ++q) {
      const int s = q * 256 + tid;
      const int row = s >> 3;
      const int cb = (s & 7) ^ (row & 7);
      gload_lds16(A0 + (size_t)row * H_DIM + k0 + cb * 8, Al + s * 8);
      gload_lds16(B0 + (size_t)row * H_DIM + k0 + cb * 8, Bl + s * 8);
    }
    __syncthreads();  // drains vmcnt(0)
#pragma unroll
    for (int kf = 0; kf < 2; ++kf) {
      const int slot = (kf * 4 + g) ^ (rl & 7);
      short8 av[4], bv[4];
#pragma unroll
      for (int i = 0; i < 4; ++i)
        av[i] = *reinterpret_cast<const short8*>(
            &Al[(wm * 64 + i * 16 + rl) * 64 + slot * 8]);
#pragma unroll
      for (int j = 0; j < 4; ++j)
        bv[j] = *reinterpret_cast<const short8*>(
            &Bl[(wn * 64 + j * 16 + rl) * 64 + slot * 8]);
      __builtin_amdgcn_s_setprio(1);
#pragma unroll
      for (int i = 0; i < 4; ++i)
#pragma unroll
        for (int j = 0; j < 4; ++j)
          acc[i][j] = __builtin_amdgcn_mfma_f32_16x16x32_bf16(
              av[i], bv[j], acc[i][j], 0, 0, 0);
      __builtin_amdgcn_s_setprio(0);
    }
  }

  // ---- epilogue: granule-level masked maxes ----
  unsigned bM[4], bN[4];
#pragma unroll
  for (int i = 0; i < 4; ++i) bM[i] = vbitsM[mt * 8 + wm * 4 + i];
#pragma unroll
  for (int j = 0; j < 4; ++j) bN[j] = vbitsN[nt * 8 + wn * 4 + j];

  // per-row max over each col-granule (16 cols); valid-col bit per lane
#pragma unroll
  for (int i = 0; i < 4; ++i)
#pragma unroll
    for (int j = 0; j < 4; ++j) {
      const unsigned cvb = bN[j];
#pragma unroll
      for (int r = 0; r < 4; ++r) {
        float pm = ((cvb >> rl) & 1u) ? acc[i][j][r] : -INFINITY;
#pragma unroll
        for (int o = 1; o < 16; o <<= 1) pm = fmaxf(pm, __shfl_xor(pm, o));
        if (rl == 0)
          rowgran[(size_t)(mt * 128 + wm * 64 + i * 16 + g * 4 + r) * GSTRIDE +
                  nt * 8 + wn * 4 + j] = pm;
      }
    }
  // per-col max over each row-granule (16 rows); valid-row bit per (g,r)
#pragma unroll
  for (int i = 0; i < 4; ++i)
#pragma unroll
    for (int j = 0; j < 4; ++j) {
      const unsigned rvb = bM[i];
      float cm = -INFINITY;
#pragma unroll
      for (int r = 0; r < 4; ++r)
        if ((rvb >> (g * 4 + r)) & 1u) cm = fmaxf(cm, acc[i][j][r]);
      cm = fmaxf(cm, __shfl_xor(cm, 16));
      cm = fmaxf(cm, __shfl_xor(cm, 32));
      if (g == 0)
        colgran[(size_t)(nt * 128 + wn * 64 + j * 16 + rl) * GSTRIDE +
                mt * 8 + wm * 4 + i] = cm;
    }
}

// ---------------- K4: final reduce — one block per (a,b) ----------------
__global__ __launch_bounds__(128) void reduce_kernel(
    const float* __restrict__ rowgran, const float* __restrict__ colgran,
    const int* __restrict__ cnts, const int* __restrict__ off1,
    const int* __restrict__ off2, float* __restrict__ out) {
  const int a = blockIdx.x >> 6, b = blockIdx.x & 63;
  const int n1 = cnts[a], n2 = cnts[64 + b];
  const int o1 = off1[a], o2 = off2[b];
  const int g2s = o2 >> 4, g2n = (n2 + 15) >> 4;
  const int g1s = o1 >> 4, g1n = (n1 + 15) >> 4;
  const int tid = threadIdx.x;
  float v1 = 0.f, v2 = 0.f;
  if (tid < n1) {
    const float* rp = rowgran + (size_t)(o1 + tid) * GSTRIDE + g2s;
    float mx = -INFINITY;
    for (int q = 0; q < g2n; ++q) mx = fmaxf(mx, rp[q]);
    v1 = mx;
  }
  if (tid < n2) {
    const float* cp = colgran + (size_t)(o2 + tid) * GSTRIDE + g1s;
    float mx = -INFINITY;
    for (int q = 0; q < g1n; ++q) mx = fmaxf(mx, cp[q]);
    v2 = mx;
  }
#pragma unroll
  for (int o = 32; o > 0; o >>= 1) {
    v1 += __shfl_down(v1, o);
    v2 += __shfl_down(v2, o);
  }
  __shared__ float s1[2], s2[2];
  if ((tid & 63) == 0) { s1[tid >> 6] = v1; s2[tid >> 6] = v2; }
  __syncthreads();
  if (tid == 0)
    out[a * 64 + b] =
        0.5f * ((s1[0] + s1[1]) / (float)n1 + (s2[0] + s2[1]) / (float)n2);
}

extern "C" void kernel_launch(void* const* d_in, const int* in_sizes, int n_in,
                              void* d_out, int out_size, void* d_ws, size_t ws_size,
                              hipStream_t stream) {
  const float* x1 = (const float*)d_in[0];
  const int* mask1 = (const int*)d_in[1];
  const float* x2 = (const float*)d_in[2];
  const int* mask2 = (const int*)d_in[3];
  float* out = (float*)d_out;

  // workspace layout (58.8 MB)
  unsigned short* xc1 = (unsigned short*)d_ws;         // 8192*768 bf16
  unsigned short* xc2 = xc1 + (size_t)8192 * H_DIM;    // 8192*768 bf16
  float* rowgran = (float*)(xc2 + (size_t)8192 * H_DIM);  // [8192][512] f32
  float* colgran = rowgran + (size_t)8192 * GSTRIDE;      // [8192][512] f32
  int* dest = (int*)(colgran + (size_t)8192 * GSTRIDE);   // 128*128
  int* cnts = dest + 128 * S_LEN;                         // 128
  int* off1 = cnts + 128;                                 // 65
  int* off2 = off1 + 65;                                  // 65
  unsigned* vbitsM = (unsigned*)(off2 + 65);              // 512
  unsigned* vbitsN = vbitsM + 512;                        // 512
  int* dims = (int*)(vbitsN + 512);                       // 4

  prep_kernel<<<128, 128, 0, stream>>>(mask1, mask2, dest, cnts);
  scan_kernel<<<1, 512, 0, stream>>>(cnts, off1, off2, vbitsM, vbitsN, dims);
  hipMemsetAsync(xc1, 0, (size_t)2 * 8192 * H_DIM * sizeof(unsigned short), stream);
  normc_kernel<<<16384, 256, 0, stream>>>(x1, x2, dest, off1, off2, xc1, xc2);
  gemm_kernel<<<4096, 256, 0, stream>>>(xc1, xc2, vbitsM, vbitsN, dims,
                                        rowgran, colgran);
  reduce_kernel<<<4096, 128, 0, stream>>>(rowgran, colgran, cnts, off1, off2, out);
}